// Round 3
// baseline (37198.456 us; speedup 1.0000x reference)
//
#include <hip/hip_runtime.h>
#include <cstdint>
#include <cstddef>

#define BDIM 256
#define NWG  256

constexpr int B_ = 64, S_ = 1024, I_ = 128, H_ = 512, O_ = 128;
constexpr size_t HB = (size_t)H_ * B_;   // 32768 floats per slab [k][b]

// ---- workspace (floats): slabs ~1.06MB, optional XT +33.5MB ----
constexpr size_t Y1_OFF  = 0;             // 2 slots (ring)
constexpr size_t Y2_OFF  = Y1_OFF + 2 * HB;
constexpr size_t RH0_OFF = Y2_OFF + 2 * HB;
constexpr size_t RH1_OFF = RH0_OFF + HB;
constexpr size_t Z0_OFF  = RH1_OFF + HB;
constexpr size_t Z1_OFF  = Z0_OFF + HB;
constexpr size_t BAR_OFF = Z1_OFF + HB;   // tree barrier: 34 lines x 64 uints
constexpr size_t BAR_WORDS = 34 * 64;
constexpr size_t SLAB_TOT = BAR_OFF + BAR_WORDS;
constexpr size_t XT_OFF  = SLAB_TOT;      // [t][i][b] transposed input
constexpr size_t XT_FLOATS = (size_t)S_ * I_ * B_;
constexpr size_t WS_NEED_XT_BYTES = (XT_OFF + XT_FLOATS) * 4;

// ---------------- LLC (agent-scope, L2-bypassing) access helpers ----------------
__device__ __forceinline__ float4 llc_load4(const float* p) {
  const unsigned long long* q = (const unsigned long long*)p;
  unsigned long long lo = __hip_atomic_load(q,     __ATOMIC_RELAXED, __HIP_MEMORY_SCOPE_AGENT);
  unsigned long long hi = __hip_atomic_load(q + 1, __ATOMIC_RELAXED, __HIP_MEMORY_SCOPE_AGENT);
  union { unsigned long long u[2]; float4 v; } c;
  c.u[0] = lo; c.u[1] = hi;
  return c.v;
}
__device__ __forceinline__ void llc_store4(float* p, float4 v) {
  union { float4 v; unsigned long long u[2]; } c; c.v = v;
  __hip_atomic_store((unsigned long long*)p,     c.u[0], __ATOMIC_RELAXED, __HIP_MEMORY_SCOPE_AGENT);
  __hip_atomic_store((unsigned long long*)p + 1, c.u[1], __ATOMIC_RELAXED, __HIP_MEMORY_SCOPE_AGENT);
}

// ---------------- init: seed ring slot-1 with h0, zero barrier ----------------
__global__ void k_init(const float* __restrict__ hidden, float* __restrict__ ws) {
  int idx = blockIdx.x * 256 + threadIdx.x;           // 2*HB + BAR_WORDS items
  if (idx < (int)(2 * HB)) {
    int l = idx >> 15, r = idx & 32767;
    int k = r >> 6, b = r & 63;
    ws[(l ? Y2_OFF : Y1_OFF) + HB + r] = hidden[b * 1024 + l * 512 + k];
  } else if (idx < (int)(2 * HB + BAR_WORDS)) {
    ((unsigned int*)(ws + BAR_OFF))[idx - 2 * HB] = 0u;
  }
}

// ---------------- input transpose: XT[t][i][b] = input[b][t][i] ----------------
__global__ void k_transpose_x(const float* __restrict__ in, float* __restrict__ Xt) {
  const size_t NQ = (size_t)B_ * S_ * I_ / 4;
  for (size_t q = (size_t)blockIdx.x * blockDim.x + threadIdx.x; q < NQ;
       q += (size_t)gridDim.x * blockDim.x) {
    int i4 = (int)(q & 31);
    int t  = (int)((q >> 5) & 1023);
    int b  = (int)(q >> 15);
    float4 v = *(const float4*)(in + ((size_t)b * 1024 + t) * 128 + i4 * 4);
    float* dst = Xt + (size_t)t * 8192 + (size_t)(i4 * 4) * 64 + b;
    dst[0] = v.x; dst[64] = v.y; dst[128] = v.z; dst[192] = v.w;
  }
}

// ---------------- fma helpers ----------------
__device__ __forceinline__ void fmas(float4& a, float s, const float4 h) {
  a.x = fmaf(s, h.x, a.x); a.y = fmaf(s, h.y, a.y);
  a.z = fmaf(s, h.z, a.z); a.w = fmaf(s, h.w, a.w);
}
// 32-column fma against a streamed (global/L2) weight row of 32 floats
__device__ __forceinline__ void fma32g(float4* acc, const float* __restrict__ wrow, float4 h) {
  #pragma unroll
  for (int g = 0; g < 8; ++g) {
    float4 w = *(const float4*)(wrow + g * 4);
    fmas(acc[g * 4 + 0], w.x, h); fmas(acc[g * 4 + 1], w.y, h);
    fmas(acc[g * 4 + 2], w.z, h); fmas(acc[g * 4 + 3], w.w, h);
  }
}
// 16-column fma against LDS weights in [c4][k] float4 tiles
__device__ __forceinline__ void fma16L(float4* acc, const float4* wB4, int k, float4 h) {
  #pragma unroll
  for (int g = 0; g < 4; ++g) {
    float4 w = wB4[g * 1024 + k];
    fmas(acc[g * 4 + 0], w.x, h); fmas(acc[g * 4 + 1], w.y, h);
    fmas(acc[g * 4 + 2], w.z, h); fmas(acc[g * 4 + 3], w.w, h);
  }
}
__device__ __forceinline__ void red32(float4& v) {   // fold upper 32 lanes onto lower
  v.x += __shfl_xor(v.x, 32); v.y += __shfl_xor(v.y, 32);
  v.z += __shfl_xor(v.z, 32); v.w += __shfl_xor(v.w, 32);
}

// ---- two-level tree barrier: 16 groups x 16 WGs, cumulative counters ----
// All mutable cross-WG data moves via agent-scope (LLC) atomics; no cache
// maintenance needed. __syncthreads() drains vmcnt(0) before lane 0 arrives.
__device__ __forceinline__ void grid_barrier(unsigned int* bar, unsigned int ph) {
  __syncthreads();
  asm volatile("" ::: "memory");
  if (threadIdx.x == 0) {
    const int g = (int)(blockIdx.x >> 4);
    unsigned int* grp_cnt  = bar + (size_t)g * 64;
    unsigned int* root_cnt = bar + 16 * 64;
    unsigned int* grp_gen  = bar + (size_t)(17 + g) * 64;
    unsigned int* root_gen = bar + 33 * 64;
    unsigned int r = __hip_atomic_fetch_add(grp_cnt, 1u, __ATOMIC_RELAXED, __HIP_MEMORY_SCOPE_AGENT);
    if (r == 16u * ph - 1u) {
      unsigned int rr = __hip_atomic_fetch_add(root_cnt, 1u, __ATOMIC_RELAXED, __HIP_MEMORY_SCOPE_AGENT);
      if (rr == 16u * ph - 1u) {
        __hip_atomic_store(root_gen, ph, __ATOMIC_RELAXED, __HIP_MEMORY_SCOPE_AGENT);
      } else {
        while (__hip_atomic_load(root_gen, __ATOMIC_RELAXED, __HIP_MEMORY_SCOPE_AGENT) < ph)
          __builtin_amdgcn_s_sleep(1);
      }
      __hip_atomic_store(grp_gen, ph, __ATOMIC_RELAXED, __HIP_MEMORY_SCOPE_AGENT);
    } else {
      while (__hip_atomic_load(grp_gen, __ATOMIC_RELAXED, __HIP_MEMORY_SCOPE_AGENT) < ph)
        __builtin_amdgcn_s_sleep(1);
    }
  }
  asm volatile("" ::: "memory");
  __syncthreads();
}

// ---------------- persistent scan ----------------
struct ScanArgs {
  float* ws;
  const float* xin;
  float* out;
  const float *Wzx0, *Wzh0, *bz0, *Wrx0, *Wrh0, *br0, *Wgx0, *Wgh0, *bg0;
  const float *Wzx1, *Wzh1, *bz1, *Wrx1, *Wrh1, *br1, *Wgx1, *Wgh1, *bg1;
  const float *Wout, *bout;
  int use_xt;
};

// WG layout (256 WGs, 256 thr = 4 waves; lane=kt 0..63, wave=batch quad):
//   phase A: mA = wg>>6 in {z0,r0,z1,r1}; colgrp cg=(wg>>2)&15 (32 cols);
//            bgrp bg=wg&3 (16 batches). Traffic = (H/32)*K*B per matrix (4x < R0).
//   phase B: L0-A WGs run g1, L1-A run g0; 32 colgrps x 16 cols x 4 bgrps.
//   outproj: folds into L1-A WGs' y2p reads (4 cols each).
__launch_bounds__(BDIM, 1)
__global__ void k_scan(ScanArgs a) {
  float* ws = a.ws;
  unsigned int* bar = (unsigned int*)(ws + BAR_OFF);

  const int tid = threadIdx.x;
  const int wg  = blockIdx.x;
  const int kt  = tid & 63;          // k-lane
  const int wv  = tid >> 6;          // wave = batch quad

  const int  mA    = wg >> 6;        // 0 z0, 1 r0, 2 z1, 3 r1
  const int  lA    = mA >> 1;
  const int  gA    = mA & 1;
  const int  cg    = (wg >> 2) & 15;
  const int  bg    = wg & 3;
  const int  jA0   = cg * 32;
  const int  b0    = bg * 16;        // batch window base
  const int  bq    = b0 + wv * 4;    // this wave's quad base
  const bool isL1A = (mA >= 2);
  const int  mB    = isL1A ? 0 : 1;  // balance: light-A WGs get heavy-B (g1)
  const int  jB0   = (((mA & 1) << 4) | cg) * 16;
  const int  KB2   = mB ? 512 : 128; // phase-B region-2 depth
  const int  jO    = ((gA << 4) | cg) * 4;  // outproj cols (isL1A only)

  // LDS: phase-B weights + outproj resident; partial buffers padded (stride 33)
  __shared__ float4 wB4[4096];        // [c4(4)][k(1024)] 64KB
  __shared__ float  wOl[2048];        // [k(512)][4] 8KB
  __shared__ float4 pL[4 * 32 * 33];  // [w][c][l] 67.6KB
  __shared__ float4 pO[16 * 33];      // [w*4+oc][l] 8.4KB

  {  // one-time gather (cached loads; immutable)
    const float* B0 = mB ? a.Wgx1 : a.Wgh0;
    const float* B1 = mB ? a.Wgh1 : a.Wgx0;
    for (int idx = tid; idx < 4096; idx += BDIM) {
      int c4 = idx >> 10, k = idx & 1023;
      int j = jB0 + c4 * 4;
      float4 w = make_float4(0.f, 0.f, 0.f, 0.f);
      if (k < 512)            w = *(const float4*)(B0 + (size_t)k * 512 + j);
      else if (k - 512 < KB2) w = *(const float4*)(B1 + (size_t)(k - 512) * 512 + j);
      wB4[idx] = w;
    }
    if (isL1A)
      for (int idx = tid; idx < 2048; idx += BDIM)
        wOl[idx] = a.Wout[(size_t)(idx >> 2) * 128 + jO + (idx & 3)];
  }
  // phase-A weights streamed from global/L2 each step (immutable, cached)
  const float* A0 = lA ? (gA ? a.Wrx1 : a.Wzx1) : (gA ? a.Wrh0 : a.Wzh0);  // k<512
  const float* A1 = lA ? (gA ? a.Wrh1 : a.Wzh1) : (gA ? a.Wrx0 : a.Wzx0);  // k>=512
  const float* bAv = lA ? (gA ? a.br1 : a.bz1) : (gA ? a.br0 : a.bz0);
  float biasA_c = 0.f, biasB_c = 0.f, boutc = 0.f;
  if (tid < 128) biasA_c = bAv[jA0 + (tid >> 2)];
  if (tid < 64)  biasB_c = (mB ? a.bg1 : a.bg0)[jB0 + (tid >> 2)];
  if (isL1A && tid >= 128 && tid < 144) boutc = a.bout[jO + ((tid >> 2) & 3)];
  __syncthreads();

  const float* XT = ws + XT_OFF;
  unsigned int ph = 1;

  for (int tau = 0; tau <= S_ + 1; ++tau) {
    const bool doL0 = (tau < S_);
    const bool doL1 = (tau >= 1) && (tau <= S_);
    const int slotP = (tau + 1) & 1;
    const int slotQ = tau & 1;
    const float* y1p = ws + Y1_OFF + (size_t)slotP * HB;   // y1[tau-1]
    const float* y2p = ws + Y2_OFF + (size_t)slotQ * HB;   // y2[tau-2]
    float* y1w = ws + Y1_OFF + (size_t)slotQ * HB;
    float* y2w = ws + Y2_OFF + (size_t)slotP * HB;

    // ================= phase A: z & r (+ fused outproj on L1 WGs) =================
    const bool actL = isL1A ? doL1 : doL0;
    const bool outW = isL1A && (tau >= 2);
    float4 acc[32];
    #pragma unroll
    for (int c = 0; c < 32; ++c) acc[c] = make_float4(0.f, 0.f, 0.f, 0.f);
    float4 accO[4];
    #pragma unroll
    for (int c = 0; c < 4; ++c) accO[c] = make_float4(0.f, 0.f, 0.f, 0.f);

    if (actL) {                       // region 1: y1p, k in [0,512)
      #pragma unroll 4
      for (int i = 0; i < 8; ++i) {
        const int k = kt + 64 * i;
        float4 h = llc_load4(y1p + (size_t)k * 64 + bq);
        fma32g(acc, A0 + (size_t)k * 512 + jA0, h);
      }
    }
    if (isL1A) {                      // region 2 L1: y2p + outproj fold
      if (actL || outW) {
        #pragma unroll 4
        for (int i = 0; i < 8; ++i) {
          const int k = kt + 64 * i;
          float4 h = llc_load4(y2p + (size_t)k * 64 + bq);
          fma32g(acc, A1 + (size_t)k * 512 + jA0, h);
          float4 wo = *(const float4*)(wOl + k * 4);
          fmas(accO[0], wo.x, h); fmas(accO[1], wo.y, h);
          fmas(accO[2], wo.z, h); fmas(accO[3], wo.w, h);
        }
      }
    } else if (actL) {                // region 2 L0: x, k in [0,128)
      if (a.use_xt) {
        const float* XTt = XT + (size_t)tau * 8192;
        #pragma unroll
        for (int i = 0; i < 2; ++i) {
          const int k = kt + 64 * i;
          float4 h = *(const float4*)(XTt + (size_t)k * 64 + bq);
          fma32g(acc, A1 + (size_t)k * 512 + jA0, h);
        }
      } else {
        #pragma unroll
        for (int i = 0; i < 2; ++i) {
          const int k = kt + 64 * i;
          float4 h;
          h.x = a.xin[(size_t)(bq + 0) * 131072 + (size_t)tau * 128 + k];
          h.y = a.xin[(size_t)(bq + 1) * 131072 + (size_t)tau * 128 + k];
          h.z = a.xin[(size_t)(bq + 2) * 131072 + (size_t)tau * 128 + k];
          h.w = a.xin[(size_t)(bq + 3) * 131072 + (size_t)tau * 128 + k];
          fma32g(acc, A1 + (size_t)k * 512 + jA0, h);
        }
      }
    }
    // reduce: fold lanes 32..63 onto 0..31, stash partials in padded LDS
    if (actL) {
      #pragma unroll
      for (int c = 0; c < 32; ++c) red32(acc[c]);
      if (kt < 32) {
        #pragma unroll
        for (int c = 0; c < 32; ++c) pL[(wv * 32 + c) * 33 + kt] = acc[c];
      }
    }
    if (outW) {
      #pragma unroll
      for (int c = 0; c < 4; ++c) red32(accO[c]);
      if (kt < 32) {
        #pragma unroll
        for (int c = 0; c < 4; ++c) pO[(wv * 4 + c) * 33 + kt] = accO[c];
      }
    }
    __syncthreads();
    if (actL && tid < 128) {
      const int c = tid >> 2, q = tid & 3;
      const float4* row = &pL[(q * 32 + c) * 33];
      float4 s = make_float4(biasA_c, biasA_c, biasA_c, biasA_c);
      #pragma unroll
      for (int l = 0; l < 32; ++l) {
        float4 p = row[l];
        s.x += p.x; s.y += p.y; s.z += p.z; s.w += p.w;
      }
      float4 v;
      v.x = 1.0f / (1.0f + __expf(-s.x)); v.y = 1.0f / (1.0f + __expf(-s.y));
      v.z = 1.0f / (1.0f + __expf(-s.z)); v.w = 1.0f / (1.0f + __expf(-s.w));
      const size_t jb = (size_t)(jA0 + c) * 64 + b0 + q * 4;
      if (gA == 0) {
        llc_store4(ws + (lA ? Z1_OFF : Z0_OFF) + jb, v);
      } else {
        float4 hp = llc_load4((lA ? y2p : y1p) + jb);
        v.x *= hp.x; v.y *= hp.y; v.z *= hp.z; v.w *= hp.w;
        llc_store4(ws + (lA ? RH1_OFF : RH0_OFF) + jb, v);
      }
    }
    if (outW && tid >= 128 && tid < 144) {
      const int oc = (tid >> 2) & 3, q = tid & 3;
      const float4* row = &pO[(q * 4 + oc) * 33];
      float4 s = make_float4(boutc, boutc, boutc, boutc);
      #pragma unroll
      for (int l = 0; l < 32; ++l) {
        float4 p = row[l];
        s.x += p.x; s.y += p.y; s.z += p.z; s.w += p.w;
      }
      const int bb = b0 + q * 4;
      const size_t ob = ((size_t)bb * 1024 + (tau - 2)) * 128 + jO + oc;
      a.out[ob]          = s.x;
      a.out[ob + 131072] = s.y;
      a.out[ob + 262144] = s.z;
      a.out[ob + 393216] = s.w;
    }

    grid_barrier(bar, ph++);   // rh/z visible grid-wide

    // ================= phase B: g and h update =================
    const bool actB = mB ? doL1 : doL0;
    float4 accB[16];
    #pragma unroll
    for (int c = 0; c < 16; ++c) accB[c] = make_float4(0.f, 0.f, 0.f, 0.f);
    if (actB) {
      const float* src1 = mB ? y1p : (ws + RH0_OFF);
      #pragma unroll 4
      for (int i = 0; i < 8; ++i) {
        const int k = kt + 64 * i;
        float4 h = llc_load4(src1 + (size_t)k * 64 + bq);
        fma16L(accB, wB4, k, h);
      }
      if (mB) {
        #pragma unroll 4
        for (int i = 0; i < 8; ++i) {
          const int k = kt + 64 * i;
          float4 h = llc_load4(ws + RH1_OFF + (size_t)k * 64 + bq);
          fma16L(accB, wB4, 512 + k, h);
        }
      } else if (a.use_xt) {
        const float* XTt = XT + (size_t)tau * 8192;
        #pragma unroll
        for (int i = 0; i < 2; ++i) {
          const int k = kt + 64 * i;
          float4 h = *(const float4*)(XTt + (size_t)k * 64 + bq);
          fma16L(accB, wB4, 512 + k, h);
        }
      } else {
        #pragma unroll
        for (int i = 0; i < 2; ++i) {
          const int k = kt + 64 * i;
          float4 h;
          h.x = a.xin[(size_t)(bq + 0) * 131072 + (size_t)tau * 128 + k];
          h.y = a.xin[(size_t)(bq + 1) * 131072 + (size_t)tau * 128 + k];
          h.z = a.xin[(size_t)(bq + 2) * 131072 + (size_t)tau * 128 + k];
          h.w = a.xin[(size_t)(bq + 3) * 131072 + (size_t)tau * 128 + k];
          fma16L(accB, wB4, 512 + k, h);
        }
      }
      #pragma unroll
      for (int c = 0; c < 16; ++c) red32(accB[c]);
      if (kt < 32) {
        #pragma unroll
        for (int c = 0; c < 16; ++c) pL[(wv * 16 + c) * 33 + kt] = accB[c];
      }
    }
    __syncthreads();
    if (actB && tid < 64) {
      const int c = tid >> 2, q = tid & 3;
      const float4* row = &pL[(q * 16 + c) * 33];
      float4 s = make_float4(biasB_c, biasB_c, biasB_c, biasB_c);
      #pragma unroll
      for (int l = 0; l < 32; ++l) {
        float4 p = row[l];
        s.x += p.x; s.y += p.y; s.z += p.z; s.w += p.w;
      }
      float4 g;
      g.x = tanhf(s.x); g.y = tanhf(s.y); g.z = tanhf(s.z); g.w = tanhf(s.w);
      const size_t jb = (size_t)(jB0 + c) * 64 + b0 + q * 4;
      float4 z  = llc_load4(ws + (mB ? Z1_OFF : Z0_OFF) + jb);
      float4 hp = llc_load4((mB ? y2p : y1p) + jb);
      float4 hn;
      hn.x = fmaf(z.x, hp.x - g.x, g.x);
      hn.y = fmaf(z.y, hp.y - g.y, g.y);
      hn.z = fmaf(z.z, hp.z - g.z, g.z);
      hn.w = fmaf(z.w, hp.w - g.w, g.w);
      llc_store4((mB ? y2w : y1w) + jb, hn);
    }

    grid_barrier(bar, ph++);   // h slabs visible for next stage
  }
}

// ---------------- final hidden states: out[BSO + b*1024 + l*512 + j] ----------------
__global__ void k_hidden(const float* __restrict__ ws, float* __restrict__ out) {
  int idx = blockIdx.x * 256 + threadIdx.x;   // 65536
  int b = idx >> 10, rem = idx & 1023, l = rem >> 9, j = rem & 511;
  // y1[1023] at slot 1; y2[1023] written stage 1024 at slot (1024+1)&1 = 1
  const float* src = ws + (l ? Y2_OFF : Y1_OFF) + HB + (size_t)j * 64 + b;
  out[(size_t)B_ * S_ * O_ + idx] = *src;
}

// ---------------- launch ----------------
extern "C" void kernel_launch(void* const* d_in, const int* in_sizes, int n_in,
                              void* d_out, int out_size, void* d_ws, size_t ws_size,
                              hipStream_t stream) {
  const float* input  = (const float*)d_in[0];
  const float* hidden = (const float*)d_in[1];
  const float* Wzx0 = (const float*)d_in[2],  *Wzh0 = (const float*)d_in[3],  *bz0 = (const float*)d_in[4];
  const float* Wrx0 = (const float*)d_in[5],  *Wrh0 = (const float*)d_in[6],  *br0 = (const float*)d_in[7];
  const float* Wgx0 = (const float*)d_in[8],  *Wgh0 = (const float*)d_in[9],  *bg0 = (const float*)d_in[10];
  const float* Wzx1 = (const float*)d_in[11], *Wzh1 = (const float*)d_in[12], *bz1 = (const float*)d_in[13];
  const float* Wrx1 = (const float*)d_in[14], *Wrh1 = (const float*)d_in[15], *br1 = (const float*)d_in[16];
  const float* Wgx1 = (const float*)d_in[17], *Wgh1 = (const float*)d_in[18], *bg1 = (const float*)d_in[19];
  const float* Wout = (const float*)d_in[20], *bout = (const float*)d_in[21];
  float* ws = (float*)d_ws;
  float* out = (float*)d_out;

  const int use_xt = (ws_size >= WS_NEED_XT_BYTES) ? 1 : 0;

  k_init<<<265, 256, 0, stream>>>(hidden, ws);
  if (use_xt) k_transpose_x<<<2048, 256, 0, stream>>>(input, ws + XT_OFF);

  ScanArgs sa{ws, input, out,
              Wzx0, Wzh0, bz0, Wrx0, Wrh0, br0, Wgx0, Wgh0, bg0,
              Wzx1, Wzh1, bz1, Wrx1, Wrh1, br1, Wgx1, Wgh1, bg1,
              Wout, bout, use_xt};
  k_scan<<<dim3(NWG), dim3(BDIM), 0, stream>>>(sa);

  k_hidden<<<256, 256, 0, stream>>>(ws, out);
}

// Round 4
// 16767.796 us; speedup vs baseline: 2.2184x; 2.2184x over previous
//
#include <hip/hip_runtime.h>
#include <cstdint>
#include <cstddef>

#define BDIM 512
#define NWG  256

constexpr int B_ = 64, S_ = 1024, I_ = 128, H_ = 512, O_ = 128;
constexpr size_t HB = (size_t)H_ * B_;   // 32768 floats per slab [k][b]

// ---- workspace (floats): slabs ~1.06MB, optional XT +33.5MB ----
constexpr size_t Y1_OFF  = 0;             // 2 slots (ring)
constexpr size_t Y2_OFF  = Y1_OFF + 2 * HB;
constexpr size_t RH0_OFF = Y2_OFF + 2 * HB;
constexpr size_t RH1_OFF = RH0_OFF + HB;
constexpr size_t Z0_OFF  = RH1_OFF + HB;
constexpr size_t Z1_OFF  = Z0_OFF + HB;
constexpr size_t BAR_OFF = Z1_OFF + HB;   // tree barrier: 34 lines x 64 uints
constexpr size_t BAR_WORDS = 34 * 64;
constexpr size_t SLAB_TOT = BAR_OFF + BAR_WORDS;
constexpr size_t XT_OFF  = SLAB_TOT;      // [t][i][b] transposed input
constexpr size_t XT_FLOATS = (size_t)S_ * I_ * B_;
constexpr size_t WS_NEED_XT_BYTES = (XT_OFF + XT_FLOATS) * 4;

// ---------------- LLC (agent-scope, L2-bypassing) access helpers ----------------
__device__ __forceinline__ float4 llc_load4(const float* p) {
  const unsigned long long* q = (const unsigned long long*)p;
  unsigned long long lo = __hip_atomic_load(q,     __ATOMIC_RELAXED, __HIP_MEMORY_SCOPE_AGENT);
  unsigned long long hi = __hip_atomic_load(q + 1, __ATOMIC_RELAXED, __HIP_MEMORY_SCOPE_AGENT);
  union { unsigned long long u[2]; float4 v; } c;
  c.u[0] = lo; c.u[1] = hi;
  return c.v;
}
__device__ __forceinline__ void llc_store4(float* p, float4 v) {
  union { float4 v; unsigned long long u[2]; } c; c.v = v;
  __hip_atomic_store((unsigned long long*)p,     c.u[0], __ATOMIC_RELAXED, __HIP_MEMORY_SCOPE_AGENT);
  __hip_atomic_store((unsigned long long*)p + 1, c.u[1], __ATOMIC_RELAXED, __HIP_MEMORY_SCOPE_AGENT);
}

// ---------------- init: seed ring slot-1 with h0, zero barrier ----------------
__global__ void k_init(const float* __restrict__ hidden, float* __restrict__ ws) {
  int idx = blockIdx.x * 256 + threadIdx.x;           // 2*HB + BAR_WORDS items
  if (idx < (int)(2 * HB)) {
    int l = idx >> 15, r = idx & 32767;
    int k = r >> 6, b = r & 63;
    ws[(l ? Y2_OFF : Y1_OFF) + HB + r] = hidden[b * 1024 + l * 512 + k];
  } else if (idx < (int)(2 * HB + BAR_WORDS)) {
    ((unsigned int*)(ws + BAR_OFF))[idx - 2 * HB] = 0u;
  }
}

// ---------------- input transpose: XT[t][i][b] = input[b][t][i] ----------------
__global__ void k_transpose_x(const float* __restrict__ in, float* __restrict__ Xt) {
  const size_t NQ = (size_t)B_ * S_ * I_ / 4;
  for (size_t q = (size_t)blockIdx.x * blockDim.x + threadIdx.x; q < NQ;
       q += (size_t)gridDim.x * blockDim.x) {
    int i4 = (int)(q & 31);
    int t  = (int)((q >> 5) & 1023);
    int b  = (int)(q >> 15);
    float4 v = *(const float4*)(in + ((size_t)b * 1024 + t) * 128 + i4 * 4);
    float* dst = Xt + (size_t)t * 8192 + (size_t)(i4 * 4) * 64 + b;
    dst[0] = v.x; dst[64] = v.y; dst[128] = v.z; dst[192] = v.w;
  }
}

// ---------------- fma helpers ----------------
__device__ __forceinline__ void fmas(float4& a, float s, const float4 h) {
  a.x = fmaf(s, h.x, a.x); a.y = fmaf(s, h.y, a.y);
  a.z = fmaf(s, h.z, a.z); a.w = fmaf(s, h.w, a.w);
}
// 16-column fma against LDS weights stored as [c4(4)][k(1024)] float4 tiles
__device__ __forceinline__ void fma16L(float4* acc, const float4* wA4, int k, float4 h) {
  #pragma unroll
  for (int g = 0; g < 4; ++g) {
    float4 w = wA4[g * 1024 + k];
    fmas(acc[g * 4 + 0], w.x, h); fmas(acc[g * 4 + 1], w.y, h);
    fmas(acc[g * 4 + 2], w.z, h); fmas(acc[g * 4 + 3], w.w, h);
  }
}
// 8-column fma against LDS weights stored as [c4(2)][k(1024)] float4 tiles
__device__ __forceinline__ void fma8L(float4* acc, const float4* wB4, int k, float4 h) {
  #pragma unroll
  for (int g = 0; g < 2; ++g) {
    float4 w = wB4[g * 1024 + k];
    fmas(acc[g * 4 + 0], w.x, h); fmas(acc[g * 4 + 1], w.y, h);
    fmas(acc[g * 4 + 2], w.z, h); fmas(acc[g * 4 + 3], w.w, h);
  }
}
// fold lane bits 3,4 (kt_lo low bits): 2 butterfly rounds
__device__ __forceinline__ void red2(float4& v) {
  v.x += __shfl_xor(v.x, 8);  v.y += __shfl_xor(v.y, 8);
  v.z += __shfl_xor(v.z, 8);  v.w += __shfl_xor(v.w, 8);
  v.x += __shfl_xor(v.x, 16); v.y += __shfl_xor(v.y, 16);
  v.z += __shfl_xor(v.z, 16); v.w += __shfl_xor(v.w, 16);
}

// ---- two-level tree barrier: 16 groups x 16 WGs, cumulative counters ----
// All mutable cross-WG data moves via agent-scope (LLC) atomics; no cache
// maintenance needed. __syncthreads() drains vmcnt(0) before lane 0 arrives.
__device__ __forceinline__ void grid_barrier(unsigned int* bar, unsigned int ph) {
  __syncthreads();
  asm volatile("" ::: "memory");
  if (threadIdx.x == 0) {
    const int g = (int)(blockIdx.x >> 4);
    unsigned int* grp_cnt  = bar + (size_t)g * 64;
    unsigned int* root_cnt = bar + 16 * 64;
    unsigned int* grp_gen  = bar + (size_t)(17 + g) * 64;
    unsigned int* root_gen = bar + 33 * 64;
    unsigned int r = __hip_atomic_fetch_add(grp_cnt, 1u, __ATOMIC_RELAXED, __HIP_MEMORY_SCOPE_AGENT);
    if (r == 16u * ph - 1u) {
      unsigned int rr = __hip_atomic_fetch_add(root_cnt, 1u, __ATOMIC_RELAXED, __HIP_MEMORY_SCOPE_AGENT);
      if (rr == 16u * ph - 1u) {
        __hip_atomic_store(root_gen, ph, __ATOMIC_RELAXED, __HIP_MEMORY_SCOPE_AGENT);
      } else {
        while (__hip_atomic_load(root_gen, __ATOMIC_RELAXED, __HIP_MEMORY_SCOPE_AGENT) < ph)
          __builtin_amdgcn_s_sleep(1);
      }
      __hip_atomic_store(grp_gen, ph, __ATOMIC_RELAXED, __HIP_MEMORY_SCOPE_AGENT);
    } else {
      while (__hip_atomic_load(grp_gen, __ATOMIC_RELAXED, __HIP_MEMORY_SCOPE_AGENT) < ph)
        __builtin_amdgcn_s_sleep(1);
    }
  }
  asm volatile("" ::: "memory");
  __syncthreads();
}

// ---------------- persistent scan ----------------
struct ScanArgs {
  float* ws;
  const float* xin;
  float* out;
  const float *Wzx0, *Wzh0, *bz0, *Wrx0, *Wrh0, *br0, *Wgx0, *Wgh0, *bg0;
  const float *Wzx1, *Wzh1, *bz1, *Wrx1, *Wrh1, *br1, *Wgx1, *Wgh1, *bg1;
  const float *Wout, *bout;
  int use_xt;
};

// WG layout (256 WGs x 512 thr = 8 waves; kt = 64 k-lanes, 8 batch-quads of 4):
//   phase A: mA = wg>>6 in {z0,r0,z1,r1}; cg=(wg>>1)&31 -> 16 cols; bg=wg&1 -> 32 batches.
//            Weights LDS-resident (C=16: 64KB). Traffic = (H/16)*K*32*4B per matrix.
//   phase B: L1-A WGs run g0 (light), L0-A run g1 (heavy); C=8 (32KB LDS).
//   outproj: 2 cols per L1-A WG, folded into the y2p dot (zero extra traffic).
__launch_bounds__(BDIM, 1)
__global__ void k_scan(ScanArgs a) {
  float* ws = a.ws;
  unsigned int* bar = (unsigned int*)(ws + BAR_OFF);

  const int tid  = threadIdx.x;
  const int wg   = blockIdx.x;
  const int lane = tid & 63;
  const int wv   = tid >> 6;          // 0..7
  const int kt   = (wv << 3) | (lane >> 3);   // 0..63 k-lane
  const int bq   = lane & 7;          // batch quad within 32-window
  const int b4   = bq << 2;
  const int hi   = lane >> 5;         // sub-partial slot after 2-round fold

  const int  mA    = wg >> 6;         // 0 z0, 1 r0, 2 z1, 3 r1
  const int  lA    = mA >> 1;
  const int  gA    = mA & 1;
  const int  cg    = (wg >> 1) & 31;
  const int  bg    = wg & 1;
  const int  jA0   = cg * 16;
  const int  b0    = bg * 32;         // batch window base
  const bool isL1A = (mA >= 2);
  const int  mB    = isL1A ? 0 : 1;   // balance: light-A WGs take heavy-B (g1)
  const int  jB0   = (((mA & 1) << 5) | cg) * 8;
  const int  jO    = (((gA << 5) | cg)) * 2;   // outproj col pair (isL1A only)

  // LDS: all weights resident + small padded partial buffer
  __shared__ float4 wA4[4 * 1024];    // [c4][k] 64KB (16 cols)
  __shared__ float4 wB4[2 * 1024];    // [c4][k] 32KB (8 cols)
  __shared__ float2 wO2[512];         // outproj col pair 4KB
  __shared__ float4 pL[18 * 8 * 17];  // partials [c][bq][slot16 pad17] 38.25KB

  {  // one-time weight gather (cached loads; immutable)
    const float* A0 = lA ? (gA ? a.Wrx1 : a.Wzx1) : (gA ? a.Wrh0 : a.Wzh0);  // region1
    const float* A1 = lA ? (gA ? a.Wrh1 : a.Wzh1) : (gA ? a.Wrx0 : a.Wzx0);  // region2
    const int KA1 = lA ? 512 : 128;
    for (int idx = tid; idx < 4096; idx += BDIM) {
      int c4 = idx >> 10, k = idx & 1023;
      int j = jA0 + c4 * 4;
      float4 w = make_float4(0.f, 0.f, 0.f, 0.f);
      if (k < 512)            w = *(const float4*)(A0 + (size_t)k * 512 + j);
      else if (k - 512 < KA1) w = *(const float4*)(A1 + (size_t)(k - 512) * 512 + j);
      wA4[idx] = w;
    }
    const float* B0 = mB ? a.Wgx1 : a.Wgh0;
    const float* B1 = mB ? a.Wgh1 : a.Wgx0;
    const int KB1 = mB ? 512 : 128;
    for (int idx = tid; idx < 2048; idx += BDIM) {
      int c4 = idx >> 10, k = idx & 1023;
      int j = jB0 + c4 * 4;
      float4 w = make_float4(0.f, 0.f, 0.f, 0.f);
      if (k < 512)            w = *(const float4*)(B0 + (size_t)k * 512 + j);
      else if (k - 512 < KB1) w = *(const float4*)(B1 + (size_t)(k - 512) * 512 + j);
      wB4[idx] = w;
    }
    if (isL1A)
      for (int idx = tid; idx < 512; idx += BDIM)
        wO2[idx] = *(const float2*)(a.Wout + (size_t)idx * 128 + jO);
  }
  const float* bAv = lA ? (gA ? a.br1 : a.bz1) : (gA ? a.br0 : a.bz0);
  float biasA = 0.f, biasB = 0.f, boutc = 0.f;
  if (tid < 128)                biasA = bAv[jA0 + (tid >> 3)];
  else if (tid < 144 && isL1A)  boutc = a.bout[jO + ((tid >> 3) & 1)];
  if (tid < 64)                 biasB = (mB ? a.bg1 : a.bg0)[jB0 + (tid >> 3)];
  __syncthreads();

  const float* XT = ws + XT_OFF;
  unsigned int ph = 1;

  for (int tau = 0; tau <= S_ + 1; ++tau) {
    const bool doL0 = (tau < S_);
    const bool doL1 = (tau >= 1) && (tau <= S_);
    const int slotP = (tau + 1) & 1;
    const int slotQ = tau & 1;
    const float* y1p = ws + Y1_OFF + (size_t)slotP * HB;   // y1[tau-1]
    const float* y2p = ws + Y2_OFF + (size_t)slotQ * HB;   // y2[tau-2]
    float* y1w = ws + Y1_OFF + (size_t)slotQ * HB;
    float* y2w = ws + Y2_OFF + (size_t)slotP * HB;

    // ================= phase A: z & r (+ fused outproj on L1 WGs) =================
    const bool actL = isL1A ? doL1 : doL0;
    const bool outW = isL1A && (tau >= 2);
    float4 acc[16];
    #pragma unroll
    for (int c = 0; c < 16; ++c) acc[c] = make_float4(0.f, 0.f, 0.f, 0.f);
    float4 accO0 = make_float4(0.f, 0.f, 0.f, 0.f);
    float4 accO1 = make_float4(0.f, 0.f, 0.f, 0.f);

    if (actL) {
      if (!isL1A) {                    // L0 x-region first (cached; overlaps LLC latency)
        if (a.use_xt) {
          const float* XTt = XT + (size_t)tau * 8192;
          #pragma unroll
          for (int i = 0; i < 2; ++i) {
            const int k = i * 64 + kt;
            float4 h = *(const float4*)(XTt + (size_t)k * 64 + b0 + b4);
            fma16L(acc, wA4, 512 + k, h);
          }
        } else {
          #pragma unroll
          for (int i = 0; i < 2; ++i) {
            const int k = i * 64 + kt;
            float4 h;
            h.x = a.xin[(size_t)(b0 + b4 + 0) * 131072 + (size_t)tau * 128 + k];
            h.y = a.xin[(size_t)(b0 + b4 + 1) * 131072 + (size_t)tau * 128 + k];
            h.z = a.xin[(size_t)(b0 + b4 + 2) * 131072 + (size_t)tau * 128 + k];
            h.w = a.xin[(size_t)(b0 + b4 + 3) * 131072 + (size_t)tau * 128 + k];
            fma16L(acc, wA4, 512 + k, h);
          }
        }
      }
      #pragma unroll 4
      for (int i = 0; i < 8; ++i) {    // region 1: y1p, k in [0,512)
        const int k = i * 64 + kt;
        float4 h = llc_load4(y1p + (size_t)k * 64 + b0 + b4);
        fma16L(acc, wA4, k, h);
      }
    }
    if (isL1A && (actL || outW)) {     // region 2 L1: y2p + outproj fold
      #pragma unroll 4
      for (int i = 0; i < 8; ++i) {
        const int k = i * 64 + kt;
        float4 h = llc_load4(y2p + (size_t)k * 64 + b0 + b4);
        fma16L(acc, wA4, 512 + k, h);
        float2 wo = wO2[k];
        fmas(accO0, wo.x, h); fmas(accO1, wo.y, h);
      }
    }
    // 2-round butterfly fold (kt_lo bits 0,1); lanes {0..7,32..39} hold sub-partials
    if (actL) {
      #pragma unroll
      for (int c = 0; c < 16; ++c) red2(acc[c]);
      if ((lane & 24) == 0) {
        #pragma unroll
        for (int c = 0; c < 16; ++c) pL[(c * 8 + bq) * 17 + (wv << 1) + hi] = acc[c];
      }
    }
    if (outW) {
      red2(accO0); red2(accO1);
      if ((lane & 24) == 0) {
        pL[(16 * 8 + bq) * 17 + (wv << 1) + hi] = accO0;
        pL[(17 * 8 + bq) * 17 + (wv << 1) + hi] = accO1;
      }
    }
    __syncthreads();
    if (tid < 128) {
      if (actL) {
        const int c = tid >> 3, bqc = tid & 7;
        const float4* row = &pL[(c * 8 + bqc) * 17];
        float4 s = make_float4(biasA, biasA, biasA, biasA);
        #pragma unroll
        for (int w = 0; w < 16; ++w) {
          float4 p = row[w];
          s.x += p.x; s.y += p.y; s.z += p.z; s.w += p.w;
        }
        float4 v;
        v.x = 1.0f / (1.0f + __expf(-s.x)); v.y = 1.0f / (1.0f + __expf(-s.y));
        v.z = 1.0f / (1.0f + __expf(-s.z)); v.w = 1.0f / (1.0f + __expf(-s.w));
        const size_t jb = (size_t)(jA0 + c) * 64 + b0 + bqc * 4;
        if (gA == 0) {
          llc_store4(ws + (lA ? Z1_OFF : Z0_OFF) + jb, v);
        } else {
          float4 hp = llc_load4((lA ? y2p : y1p) + jb);
          v.x *= hp.x; v.y *= hp.y; v.z *= hp.z; v.w *= hp.w;
          llc_store4(ws + (lA ? RH1_OFF : RH0_OFF) + jb, v);
        }
      }
    } else if (tid < 144 && outW) {
      const int oc = (tid >> 3) & 1, bqc = tid & 7;
      const float4* row = &pL[((16 + oc) * 8 + bqc) * 17];
      float4 s = make_float4(boutc, boutc, boutc, boutc);
      #pragma unroll
      for (int w = 0; w < 16; ++w) {
        float4 p = row[w];
        s.x += p.x; s.y += p.y; s.z += p.z; s.w += p.w;
      }
      const int bb = b0 + bqc * 4;
      const size_t ob = ((size_t)bb * 1024 + (tau - 2)) * 128 + jO + oc;
      a.out[ob]          = s.x;
      a.out[ob + 131072] = s.y;
      a.out[ob + 262144] = s.z;
      a.out[ob + 393216] = s.w;
    }

    grid_barrier(bar, ph++);   // rh/z visible grid-wide

    // ================= phase B: g and h update =================
    const bool actB = mB ? doL1 : doL0;
    float4 accB[8];
    #pragma unroll
    for (int c = 0; c < 8; ++c) accB[c] = make_float4(0.f, 0.f, 0.f, 0.f);
    if (actB) {
      if (!mB) {                       // g0: RH0 (512) + x (128)
        if (a.use_xt) {
          const float* XTt = XT + (size_t)tau * 8192;
          #pragma unroll
          for (int i = 0; i < 2; ++i) {
            const int k = i * 64 + kt;
            float4 h = *(const float4*)(XTt + (size_t)k * 64 + b0 + b4);
            fma8L(accB, wB4, 512 + k, h);
          }
        } else {
          #pragma unroll
          for (int i = 0; i < 2; ++i) {
            const int k = i * 64 + kt;
            float4 h;
            h.x = a.xin[(size_t)(b0 + b4 + 0) * 131072 + (size_t)tau * 128 + k];
            h.y = a.xin[(size_t)(b0 + b4 + 1) * 131072 + (size_t)tau * 128 + k];
            h.z = a.xin[(size_t)(b0 + b4 + 2) * 131072 + (size_t)tau * 128 + k];
            h.w = a.xin[(size_t)(b0 + b4 + 3) * 131072 + (size_t)tau * 128 + k];
            fma8L(accB, wB4, 512 + k, h);
          }
        }
        #pragma unroll 4
        for (int i = 0; i < 8; ++i) {
          const int k = i * 64 + kt;
          float4 h = llc_load4(ws + RH0_OFF + (size_t)k * 64 + b0 + b4);
          fma8L(accB, wB4, k, h);
        }
      } else {                         // g1: y1p (512) + RH1 (512)
        #pragma unroll 4
        for (int i = 0; i < 8; ++i) {
          const int k = i * 64 + kt;
          float4 h = llc_load4(y1p + (size_t)k * 64 + b0 + b4);
          fma8L(accB, wB4, k, h);
        }
        #pragma unroll 4
        for (int i = 0; i < 8; ++i) {
          const int k = i * 64 + kt;
          float4 h = llc_load4(ws + RH1_OFF + (size_t)k * 64 + b0 + b4);
          fma8L(accB, wB4, 512 + k, h);
        }
      }
      #pragma unroll
      for (int c = 0; c < 8; ++c) red2(accB[c]);
      if ((lane & 24) == 0) {
        #pragma unroll
        for (int c = 0; c < 8; ++c) pL[(c * 8 + bq) * 17 + (wv << 1) + hi] = accB[c];
      }
    }
    __syncthreads();
    if (actB && tid < 64) {
      const int c = tid >> 3, bqc = tid & 7;
      const float4* row = &pL[(c * 8 + bqc) * 17];
      float4 s = make_float4(biasB, biasB, biasB, biasB);
      #pragma unroll
      for (int w = 0; w < 16; ++w) {
        float4 p = row[w];
        s.x += p.x; s.y += p.y; s.z += p.z; s.w += p.w;
      }
      float4 g;
      g.x = tanhf(s.x); g.y = tanhf(s.y); g.z = tanhf(s.z); g.w = tanhf(s.w);
      const size_t jb = (size_t)(jB0 + c) * 64 + b0 + bqc * 4;
      float4 z  = llc_load4(ws + (mB ? Z1_OFF : Z0_OFF) + jb);
      float4 hp = llc_load4((mB ? y2p : y1p) + jb);
      float4 hn;
      hn.x = fmaf(z.x, hp.x - g.x, g.x);
      hn.y = fmaf(z.y, hp.y - g.y, g.y);
      hn.z = fmaf(z.z, hp.z - g.z, g.z);
      hn.w = fmaf(z.w, hp.w - g.w, g.w);
      llc_store4((mB ? y2w : y1w) + jb, hn);
    }

    grid_barrier(bar, ph++);   // h slabs visible for next stage
  }
}

// ---------------- final hidden states: out[BSO + b*1024 + l*512 + j] ----------------
__global__ void k_hidden(const float* __restrict__ ws, float* __restrict__ out) {
  int idx = blockIdx.x * 256 + threadIdx.x;   // 65536
  int b = idx >> 10, rem = idx & 1023, l = rem >> 9, j = rem & 511;
  // y1[1023] at slot 1; y2[1023] written stage 1024 at slot (1024+1)&1 = 1
  const float* src = ws + (l ? Y2_OFF : Y1_OFF) + HB + (size_t)j * 64 + b;
  out[(size_t)B_ * S_ * O_ + idx] = *src;
}

// ---------------- launch ----------------
extern "C" void kernel_launch(void* const* d_in, const int* in_sizes, int n_in,
                              void* d_out, int out_size, void* d_ws, size_t ws_size,
                              hipStream_t stream) {
  const float* input  = (const float*)d_in[0];
  const float* hidden = (const float*)d_in[1];
  const float* Wzx0 = (const float*)d_in[2],  *Wzh0 = (const float*)d_in[3],  *bz0 = (const float*)d_in[4];
  const float* Wrx0 = (const float*)d_in[5],  *Wrh0 = (const float*)d_in[6],  *br0 = (const float*)d_in[7];
  const float* Wgx0 = (const float*)d_in[8],  *Wgh0 = (const float*)d_in[9],  *bg0 = (const float*)d_in[10];
  const float* Wzx1 = (const float*)d_in[11], *Wzh1 = (const float*)d_in[12], *bz1 = (const float*)d_in[13];
  const float* Wrx1 = (const float*)d_in[14], *Wrh1 = (const float*)d_in[15], *br1 = (const float*)d_in[16];
  const float* Wgx1 = (const float*)d_in[17], *Wgh1 = (const float*)d_in[18], *bg1 = (const float*)d_in[19];
  const float* Wout = (const float*)d_in[20], *bout = (const float*)d_in[21];
  float* ws = (float*)d_ws;
  float* out = (float*)d_out;

  const int use_xt = (ws_size >= WS_NEED_XT_BYTES) ? 1 : 0;

  k_init<<<265, 256, 0, stream>>>(hidden, ws);
  if (use_xt) k_transpose_x<<<2048, 256, 0, stream>>>(input, ws + XT_OFF);

  ScanArgs sa{ws, input, out,
              Wzx0, Wzh0, bz0, Wrx0, Wrh0, br0, Wgx0, Wgh0, bg0,
              Wzx1, Wzh1, bz1, Wrx1, Wrh1, br1, Wgx1, Wgh1, bg1,
              Wout, bout, use_xt};
  k_scan<<<dim3(NWG), dim3(BDIM), 0, stream>>>(sa);

  k_hidden<<<256, 256, 0, stream>>>(ws, out);
}